// Round 1
// baseline (6300.911 us; speedup 1.0000x reference)
//
#include <hip/hip_runtime.h>
#include <math.h>

#define B_ 128
#define SEQ_ 64
#define CH_ 256
#define PARTS_ 16
#define HID_ 64

// One block per (b, p). 256 threads = 4 waves.
// LDS: xs[256][64] (x slice), h1s[64][64], h2s[64][64] = 96 KB -> 1 block/CU.
__global__ __launch_bounds__(256) void tfa_fused(
    const float* __restrict__ x,
    const float* __restrict__ W1a,
    const float* __restrict__ W1b,
    const float* __restrict__ W2a,
    const float* __restrict__ W2b,
    float* __restrict__ out)
{
    __shared__ float xs[CH_ * SEQ_];
    __shared__ float h1s[HID_ * SEQ_];
    __shared__ float h2s[HID_ * SEQ_];

    const int blk = blockIdx.x;
    const int b = blk >> 4;
    const int p = blk & 15;
    const int t = threadIdx.x;
    const int lane = t & 63;
    const int wid = __builtin_amdgcn_readfirstlane(t >> 6);  // wave id 0..3, SGPR

    // ---- load x tile: xs[c][s] = x[b][s][c][p]  (stride-16 gather; L2/L3 absorbs)
    {
        const float* xb = x + (size_t)b * (SEQ_ * CH_ * PARTS_) + p;
        const int s = lane;
        for (int cc = wid; cc < CH_; cc += 4) {
            xs[cc * SEQ_ + s] = xb[((size_t)s * CH_ + cc) * PARTS_];
        }
    }
    __syncthreads();

    const int s = lane;
    const int sm1 = (s > 0) ? s - 1 : 0;
    const int sp1 = (s < 63) ? s + 1 : 63;
    const int sm2 = (s > 1) ? s - 2 : 0;
    const int sp2 = (s < 62) ? s + 2 : 63;
    const float zm1 = (s > 0) ? 1.f : 0.f;
    const float zp1 = (s < 63) ? 1.f : 0.f;
    const float zm2 = (s > 1) ? 1.f : 0.f;
    const float zp2 = (s < 62) ? 1.f : 0.f;

    // ---- stage 1: both 3-tap convs CH->HID; wave computes hid rows wid*16..wid*16+15
    {
        float acc1[16], acc2[16];
        #pragma unroll
        for (int j = 0; j < 16; ++j) { acc1[j] = 0.f; acc2[j] = 0.f; }
        const float* w1 = W1a + ((size_t)p * HID_ + wid * 16) * (CH_ * 3);
        const float* w2 = W2a + ((size_t)p * HID_ + wid * 16) * (CH_ * 3);
        for (int c = 0; c < CH_; ++c) {
            const float x0 = xs[c * SEQ_ + s];
            const float xm = xs[c * SEQ_ + sm1] * zm1;
            const float xp = xs[c * SEQ_ + sp1] * zp1;
            #pragma unroll
            for (int j = 0; j < 16; ++j) {
                const float* wj = w1 + (size_t)j * (CH_ * 3) + c * 3;   // wave-uniform -> s_load
                acc1[j] = fmaf(xm, wj[0], fmaf(x0, wj[1], fmaf(xp, wj[2], acc1[j])));
                const float* vj = w2 + (size_t)j * (CH_ * 3) + c * 3;
                acc2[j] = fmaf(xm, vj[0], fmaf(x0, vj[1], fmaf(xp, vj[2], acc2[j])));
            }
        }
        #pragma unroll
        for (int j = 0; j < 16; ++j) {
            float v1 = acc1[j]; v1 = (v1 > 0.f) ? v1 : 0.01f * v1;   // LeakyReLU
            h1s[(wid * 16 + j) * SEQ_ + s] = v1;
            float v2 = acc2[j]; v2 = (v2 > 0.f) ? v2 : 0.01f * v2;
            h2s[(wid * 16 + j) * SEQ_ + s] = v2;
        }
    }
    __syncthreads();

    // ---- stage 2: per wave 64 c-rows, in 4 chunks of 16
    for (int chunk = 0; chunk < 4; ++chunk) {
        const int c0 = wid * 64 + chunk * 16;
        float l1[16], l2[16];
        #pragma unroll
        for (int j = 0; j < 16; ++j) { l1[j] = 0.f; l2[j] = 0.f; }
        const float* wb1 = W1b + ((size_t)p * CH_ + c0) * HID_;        // [16][64]
        const float* wb2 = W2b + ((size_t)p * CH_ + c0) * (HID_ * 3);  // [16][64][3]
        for (int h = 0; h < HID_; ++h) {
            const float a0 = h1s[h * SEQ_ + s];
            const float b0 = h2s[h * SEQ_ + s];
            const float bm = h2s[h * SEQ_ + sm1] * zm1;
            const float bp = h2s[h * SEQ_ + sp1] * zp1;
            #pragma unroll
            for (int j = 0; j < 16; ++j) {
                l1[j] = fmaf(a0, wb1[(size_t)j * HID_ + h], l1[j]);
                const float* wv = wb2 + (size_t)j * (HID_ * 3) + h * 3;
                l2[j] = fmaf(bm, wv[0], fmaf(b0, wv[1], fmaf(bp, wv[2], l2[j])));
            }
        }
        float vout = 0.f;
        #pragma unroll
        for (int j = 0; j < 16; ++j) {
            const int c = c0 + j;
            const float x0  = xs[c * SEQ_ + s];
            const float am1 = xs[c * SEQ_ + sm1];
            const float ap1 = xs[c * SEQ_ + sp1];
            const float am2 = xs[c * SEQ_ + sm2];
            const float ap2 = xs[c * SEQ_ + sp2];
            // avg pools: count_include_pad -> always /k, zero-padded
            const float avg3 = (am1 * zm1 + x0 + ap1 * zp1) * (1.f / 3.f);
            const float avg5 = (am2 * zm2 + am1 * zm1 + x0 + ap1 * zp1 + ap2 * zp2) * 0.2f;
            // max pools: -inf padding
            float mx3 = x0;
            mx3 = fmaxf(mx3, (s > 0)  ? am1 : -INFINITY);
            mx3 = fmaxf(mx3, (s < 63) ? ap1 : -INFINITY);
            float mx5 = mx3;
            mx5 = fmaxf(mx5, (s > 1)  ? am2 : -INFINITY);
            mx5 = fmaxf(mx5, (s < 62) ? ap2 : -INFINITY);
            const float g1 = 1.f / (1.f + __expf(-l1[j]));
            const float g2 = 1.f / (1.f + __expf(-l2[j]));
            float m = (avg3 + mx3) * g1 + (avg5 + mx5) * g2;
            // max over s across the 64-lane wave
            #pragma unroll
            for (int off = 32; off >= 1; off >>= 1)
                m = fmaxf(m, __shfl_xor(m, off, 64));
            if (lane == j) vout = m;
        }
        if (lane < 16)
            out[((size_t)b * PARTS_ + p) * CH_ + c0 + lane] = vout;
    }
}

extern "C" void kernel_launch(void* const* d_in, const int* in_sizes, int n_in,
                              void* d_out, int out_size, void* d_ws, size_t ws_size,
                              hipStream_t stream) {
    const float* x   = (const float*)d_in[0];
    const float* W1a = (const float*)d_in[1];
    const float* W1b = (const float*)d_in[2];
    const float* W2a = (const float*)d_in[3];
    const float* W2b = (const float*)d_in[4];
    float* out = (float*)d_out;

    tfa_fused<<<dim3(B_ * PARTS_), dim3(256), 0, stream>>>(x, W1a, W1b, W2a, W2b, out);
}

// Round 2
// 1130.650 us; speedup vs baseline: 5.5728x; 5.5728x over previous
//
#include <hip/hip_runtime.h>
#include <math.h>

#define B_ 128
#define SEQ_ 64
#define CH_ 256
#define PARTS_ 16
#define HID_ 64
#define HPAD 68   // padded row stride for h1s/h2s (272 B -> bank-conflict-free)

// One block per (b, p). 256 threads = 4 waves, 1 block/CU (98 KB LDS).
// Lane mapping everywhere: jj = lane&15 (j or c offset), sg = lane>>4 (s-quarter),
// each lane register-blocks 16 consecutive s positions.
__global__ __launch_bounds__(256, 1) void tfa_fused(
    const float* __restrict__ x,
    const float* __restrict__ W1a,
    const float* __restrict__ W1b,
    const float* __restrict__ W2a,
    const float* __restrict__ W2b,
    float* __restrict__ out)
{
    __shared__ float xs[CH_ * SEQ_];
    __shared__ float h1s[HID_ * HPAD];
    __shared__ float h2s[HID_ * HPAD];

    const int blk = blockIdx.x;
    const int b = blk >> 4;
    const int p = blk & 15;
    const int t = threadIdx.x;
    const int lane = t & 63;
    const int wid = __builtin_amdgcn_readfirstlane(t >> 6);  // wave id 0..3

    // ---- load x tile: xs[c][s] = x[b][s][c][p]
    {
        const float* xb = x + (size_t)b * (SEQ_ * CH_ * PARTS_) + p;
        const int s = lane;
        for (int cc = wid; cc < CH_; cc += 4)
            xs[cc * SEQ_ + s] = xb[((size_t)s * CH_ + cc) * PARTS_];
    }
    __syncthreads();

    const int jj = lane & 15;
    const int sg = lane >> 4;
    const int sbase = sg << 4;
    const float fl = (sg > 0) ? 1.f : 0.f;   // left halo valid
    const float fr = (sg < 3) ? 1.f : 0.f;   // right halo valid
    const int il  = (sg > 0) ? -1 : 0;       // safe left offset
    const int ir  = (sg < 3) ? 16 : 0;       // safe right offset
    const int ir2 = (sg < 3) ? 17 : 0;
    const int il2 = (sg > 0) ? -2 : 0;

    // ---- stage 1: both 3-tap convs CH->HID (per-lane j, 16 s in registers)
    {
        const int j0 = wid * 16 + jj;
        float a1[16], a2[16];
        #pragma unroll
        for (int i = 0; i < 16; ++i) { a1[i] = 0.f; a2[i] = 0.f; }
        const float* w1p = W1a + (size_t)(p * HID_ + j0) * (CH_ * 3);
        const float* w2p = W2a + (size_t)(p * HID_ + j0) * (CH_ * 3);

        #pragma unroll 4
        for (int c = 0; c < CH_; ++c) {
            const float* xrow = &xs[c * SEQ_ + sbase];
            float xv[18];
            {
                float4 q;
                q = *(const float4*)(xrow);      xv[1]=q.x; xv[2]=q.y; xv[3]=q.z; xv[4]=q.w;
                q = *(const float4*)(xrow + 4);  xv[5]=q.x; xv[6]=q.y; xv[7]=q.z; xv[8]=q.w;
                q = *(const float4*)(xrow + 8);  xv[9]=q.x; xv[10]=q.y; xv[11]=q.z; xv[12]=q.w;
                q = *(const float4*)(xrow + 12); xv[13]=q.x; xv[14]=q.y; xv[15]=q.z; xv[16]=q.w;
            }
            xv[0]  = xrow[il] * fl;
            xv[17] = xrow[ir] * fr;

            const float w10 = w1p[c*3+0], w11 = w1p[c*3+1], w12 = w1p[c*3+2];
            const float w20 = w2p[c*3+0], w21 = w2p[c*3+1], w22 = w2p[c*3+2];
            #pragma unroll
            for (int i = 0; i < 16; ++i) {
                a1[i] = fmaf(xv[i], w10, fmaf(xv[i+1], w11, fmaf(xv[i+2], w12, a1[i])));
                a2[i] = fmaf(xv[i], w20, fmaf(xv[i+1], w21, fmaf(xv[i+2], w22, a2[i])));
            }
        }

        float* h1w = &h1s[j0 * HPAD + sbase];
        float* h2w = &h2s[j0 * HPAD + sbase];
        #pragma unroll
        for (int q4 = 0; q4 < 4; ++q4) {
            float4 v1, v2;
            float u;
            u = a1[4*q4+0]; v1.x = (u > 0.f) ? u : 0.01f * u;
            u = a1[4*q4+1]; v1.y = (u > 0.f) ? u : 0.01f * u;
            u = a1[4*q4+2]; v1.z = (u > 0.f) ? u : 0.01f * u;
            u = a1[4*q4+3]; v1.w = (u > 0.f) ? u : 0.01f * u;
            u = a2[4*q4+0]; v2.x = (u > 0.f) ? u : 0.01f * u;
            u = a2[4*q4+1]; v2.y = (u > 0.f) ? u : 0.01f * u;
            u = a2[4*q4+2]; v2.z = (u > 0.f) ? u : 0.01f * u;
            u = a2[4*q4+3]; v2.w = (u > 0.f) ? u : 0.01f * u;
            *(float4*)(h1w + 4*q4) = v1;
            *(float4*)(h2w + 4*q4) = v2;
        }
    }
    __syncthreads();

    // ---- stage 2: conv1x1 (br1) + conv3 (br2) HID->CH, all 64 c per wave in one h-loop
    {
        const int cbase = wid * 64;
        float l1[4][16], l2[4][16];
        #pragma unroll
        for (int ch = 0; ch < 4; ++ch)
            #pragma unroll
            for (int i = 0; i < 16; ++i) { l1[ch][i] = 0.f; l2[ch][i] = 0.f; }

        #pragma unroll 2
        for (int h = 0; h < HID_; ++h) {
            const float* h1row = &h1s[h * HPAD + sbase];
            const float* h2row = &h2s[h * HPAD + sbase];
            float hv1[16], hv2[18];
            {
                float4 q;
                q = *(const float4*)(h1row);      hv1[0]=q.x; hv1[1]=q.y; hv1[2]=q.z; hv1[3]=q.w;
                q = *(const float4*)(h1row + 4);  hv1[4]=q.x; hv1[5]=q.y; hv1[6]=q.z; hv1[7]=q.w;
                q = *(const float4*)(h1row + 8);  hv1[8]=q.x; hv1[9]=q.y; hv1[10]=q.z; hv1[11]=q.w;
                q = *(const float4*)(h1row + 12); hv1[12]=q.x; hv1[13]=q.y; hv1[14]=q.z; hv1[15]=q.w;
                q = *(const float4*)(h2row);      hv2[1]=q.x; hv2[2]=q.y; hv2[3]=q.z; hv2[4]=q.w;
                q = *(const float4*)(h2row + 4);  hv2[5]=q.x; hv2[6]=q.y; hv2[7]=q.z; hv2[8]=q.w;
                q = *(const float4*)(h2row + 8);  hv2[9]=q.x; hv2[10]=q.y; hv2[11]=q.z; hv2[12]=q.w;
                q = *(const float4*)(h2row + 12); hv2[13]=q.x; hv2[14]=q.y; hv2[15]=q.z; hv2[16]=q.w;
            }
            hv2[0]  = h2row[il] * fl;
            hv2[17] = h2row[ir] * fr;

            #pragma unroll
            for (int ch = 0; ch < 4; ++ch) {
                const int c = cbase + ch * 16 + jj;
                const float wb1 = W1b[((size_t)p * CH_ + c) * HID_ + h];
                const float* w2q = W2b + ((size_t)(p * CH_ + c) * HID_ + h) * 3;
                const float wa = w2q[0], wb = w2q[1], wc = w2q[2];
                #pragma unroll
                for (int i = 0; i < 16; ++i) {
                    l1[ch][i] = fmaf(hv1[i], wb1, l1[ch][i]);
                    l2[ch][i] = fmaf(hv2[i], wa, fmaf(hv2[i+1], wb, fmaf(hv2[i+2], wc, l2[ch][i])));
                }
            }
        }

        // ---- epilogue: pools + sigmoid gates + temporal max
        #pragma unroll
        for (int ch = 0; ch < 4; ++ch) {
            const int c = cbase + ch * 16 + jj;
            const float* xrow = &xs[c * SEQ_ + sbase];
            float xp[20];
            {
                float4 q;
                q = *(const float4*)(xrow);      xp[2]=q.x; xp[3]=q.y; xp[4]=q.z; xp[5]=q.w;
                q = *(const float4*)(xrow + 4);  xp[6]=q.x; xp[7]=q.y; xp[8]=q.z; xp[9]=q.w;
                q = *(const float4*)(xrow + 8);  xp[10]=q.x; xp[11]=q.y; xp[12]=q.z; xp[13]=q.w;
                q = *(const float4*)(xrow + 12); xp[14]=q.x; xp[15]=q.y; xp[16]=q.z; xp[17]=q.w;
            }
            xp[0]  = xrow[il2] * fl;
            xp[1]  = xrow[il]  * fl;
            xp[18] = xrow[ir]  * fr;
            xp[19] = xrow[ir2] * fr;

            float mloc = -INFINITY;
            #pragma unroll
            for (int i = 0; i < 16; ++i) {
                const int s = sbase + i;
                const float x0  = xp[i+2];
                const float am1 = xp[i+1], ap1 = xp[i+3];
                const float am2 = xp[i],   ap2 = xp[i+4];
                const float avg3 = (am1 + x0 + ap1) * (1.f / 3.f);
                const float avg5 = (am2 + am1 + x0 + ap1 + ap2) * 0.2f;
                float mx3 = x0;
                if (s > 0)  mx3 = fmaxf(mx3, am1);
                if (s < 63) mx3 = fmaxf(mx3, ap1);
                float mx5 = mx3;
                if (s > 1)  mx5 = fmaxf(mx5, am2);
                if (s < 62) mx5 = fmaxf(mx5, ap2);
                const float g1 = 1.f / (1.f + __expf(-l1[ch][i]));
                const float g2 = 1.f / (1.f + __expf(-l2[ch][i]));
                const float m = (avg3 + mx3) * g1 + (avg5 + mx5) * g2;
                mloc = fmaxf(mloc, m);
            }
            mloc = fmaxf(mloc, __shfl_xor(mloc, 16, 64));
            mloc = fmaxf(mloc, __shfl_xor(mloc, 32, 64));
            if (sg == 0)
                out[(size_t)blk * CH_ + c] = mloc;
        }
    }
}

extern "C" void kernel_launch(void* const* d_in, const int* in_sizes, int n_in,
                              void* d_out, int out_size, void* d_ws, size_t ws_size,
                              hipStream_t stream) {
    const float* x   = (const float*)d_in[0];
    const float* W1a = (const float*)d_in[1];
    const float* W1b = (const float*)d_in[2];
    const float* W2a = (const float*)d_in[3];
    const float* W2b = (const float*)d_in[4];
    float* out = (float*)d_out;

    tfa_fused<<<dim3(B_ * PARTS_), dim3(256), 0, stream>>>(x, W1a, W1b, W2a, W2b, out);
}

// Round 3
// 615.358 us; speedup vs baseline: 10.2394x; 1.8374x over previous
//
#include <hip/hip_runtime.h>
#include <hip/hip_bf16.h>
#include <math.h>

#define B_ 128
#define SEQ_ 64
#define CH_ 256
#define PARTS_ 16
#define HID_ 64

typedef __attribute__((ext_vector_type(8))) short bf16x8;
typedef __attribute__((ext_vector_type(4))) float f32x4;

// ---- ws layout (bf16 elements) ----
// Wa1[p][j][k1], k1 = tap*256 + c   : 16*64*768
// Wa2[p][j][k1]                     : 16*64*768
// Wb1[p][c][h]                      : 16*256*64
// Wb2[p][c][k2], k2 = tap*64 + h    : 16*256*192
#define WA1_OFF 0
#define WA2_OFF (16 * 64 * 768)
#define WB1_OFF (2 * 16 * 64 * 768)
#define WB2_OFF (2 * 16 * 64 * 768 + 16 * 256 * 64)
#define WS_ELEMS (2 * 16 * 64 * 768 + 16 * 256 * 64 + 16 * 256 * 192)
#define WS_BYTES ((size_t)WS_ELEMS * 2)

__device__ __forceinline__ ushort f2bf(float f) {
    __hip_bfloat16 h = __float2bfloat16(f);
    return *reinterpret_cast<ushort*>(&h);
}
__device__ __forceinline__ float bf2f(ushort u) {
    __hip_bfloat16 h;
    *reinterpret_cast<ushort*>(&h) = u;
    return __bfloat162float(h);
}

// ================= pre-pass: reorder weights to bf16 MFMA-A layouts =================
__global__ __launch_bounds__(256) void prep_weights(
    const float* __restrict__ W1a, const float* __restrict__ W1b,
    const float* __restrict__ W2a, const float* __restrict__ W2b,
    ushort* __restrict__ ws)
{
    const int NA  = 16 * 64 * 768;
    const int NB1 = 16 * 256 * 64;
    const int NB2 = 16 * 256 * 192;
    int idx = blockIdx.x * 256 + threadIdx.x;
    if (idx < NA) {
        int k = idx % 768, j = (idx / 768) % 64, p = idx / (768 * 64);
        int tap = k >> 8, c = k & 255;
        size_t src = ((size_t)(p * 64 + j) * 256 + c) * 3 + tap;
        ws[WA1_OFF + idx] = f2bf(W1a[src]);
        ws[WA2_OFF + idx] = f2bf(W2a[src]);
    } else if (idx < NA + NB1) {
        int i2 = idx - NA;
        ws[WB1_OFF + i2] = f2bf(W1b[i2]);   // already [p][c][h]
    } else if (idx < NA + NB1 + NB2) {
        int i2 = idx - NA - NB1;            // over [p][c][k2]
        int k = i2 % 192, c = (i2 / 192) % 256, p = i2 / (192 * 256);
        int tap = k / 64, h = k & 63;
        ws[WB2_OFF + i2] = f2bf(W2b[((size_t)(p * 256 + c) * 64 + h) * 3 + tap]);
    }
}

// ================= main fused kernel (MFMA path) =================
#define XSTRIDE 264   // bf16 elems per Xt row (256 + 8 pad) -> 528 B, bank shift 4
#define XROWS   68    // rows = s' + 2, s' in [-2, 65]; rows 0,1,66,67 zero
#define HSTR    72    // bf16 elems per Ht row (64 + 8 pad)

__global__ __launch_bounds__(256, 2) void tfa_mfma(
    const float* __restrict__ x,
    const ushort* __restrict__ ws,
    float* __restrict__ out)
{
    __shared__ __align__(16) ushort Xt[XROWS * XSTRIDE];      // 35.9 KB
    __shared__ __align__(16) ushort Ht1[64 * HSTR];           // 9.2 KB  row = s
    __shared__ __align__(16) ushort Ht2[66 * HSTR];           // 9.5 KB  row = s'+1, s' in [-1,64]
    __shared__ float pm[4][CH_];                              // 4 KB

    const int blk = blockIdx.x;
    const int b = blk >> 4;
    const int p = blk & 15;
    const int t = threadIdx.x;
    const int lane = t & 63;
    const int wid = __builtin_amdgcn_readfirstlane(t >> 6);   // wave id = s-tile
    const int nlane = lane & 15;                              // N index within tile
    const int klane = lane >> 4;                              // k-group
    const int s0 = wid << 4;

    // ---- zero pad rows ----
    for (int i = t; i < 2 * XSTRIDE; i += 256) {
        Xt[i] = 0;                          // rows 0,1
        Xt[66 * XSTRIDE + i] = 0;           // rows 66,67
    }
    for (int i = t; i < HSTR; i += 256) {
        Ht2[i] = 0;                         // row 0
        Ht2[65 * HSTR + i] = 0;             // row 65
    }

    // ---- stage x slice: Xt[s+2][c] = bf16(x[b][s][c][p]) ----
    {
        const float* xb = x + (size_t)b * (SEQ_ * CH_ * PARTS_) + p;
        for (int cc = wid; cc < CH_; cc += 4) {
            float v = xb[((size_t)lane * CH_ + cc) * PARTS_];
            Xt[(lane + 2) * XSTRIDE + cc] = f2bf(v);
        }
    }
    __syncthreads();

    // ---- stage 1: H[64j][64s] = Wa . im2col(X), two branches; wave owns s-tile ----
    {
        f32x4 acc1[4], acc2[4];
        #pragma unroll
        for (int jt = 0; jt < 4; ++jt) { acc1[jt] = {0.f, 0.f, 0.f, 0.f}; acc2[jt] = {0.f, 0.f, 0.f, 0.f}; }

        const ushort* wa1 = ws + WA1_OFF + (size_t)p * 64 * 768;
        const ushort* wa2 = ws + WA2_OFF + (size_t)p * 64 * 768;
        const int koff = klane << 3;

        for (int kk = 0; kk < 24; ++kk) {
            const int tap = kk >> 3;
            const int c0 = ((kk & 7) << 5) + koff;
            const int row = s0 + nlane + tap + 1;   // s' = s + tap - 1 -> row = s' + 2
            bf16x8 bfrag = *reinterpret_cast<const bf16x8*>(&Xt[row * XSTRIDE + c0]);
            const int ka = kk * 32 + koff;
            #pragma unroll
            for (int jt = 0; jt < 4; ++jt) {
                const int j = (jt << 4) + nlane;
                bf16x8 a1 = *reinterpret_cast<const bf16x8*>(&wa1[(size_t)j * 768 + ka]);
                acc1[jt] = __builtin_amdgcn_mfma_f32_16x16x32_bf16(a1, bfrag, acc1[jt], 0, 0, 0);
                bf16x8 a2 = *reinterpret_cast<const bf16x8*>(&wa2[(size_t)j * 768 + ka]);
                acc2[jt] = __builtin_amdgcn_mfma_f32_16x16x32_bf16(a2, bfrag, acc2[jt], 0, 0, 0);
            }
        }

        // LeakyReLU -> bf16 -> Ht   (D: row j = jt*16 + klane*4 + r, col s = s0 + nlane)
        const int s = s0 + nlane;
        #pragma unroll
        for (int jt = 0; jt < 4; ++jt) {
            #pragma unroll
            for (int r = 0; r < 4; ++r) {
                const int j = (jt << 4) + (klane << 2) + r;
                float v1 = acc1[jt][r]; v1 = (v1 > 0.f) ? v1 : 0.01f * v1;
                Ht1[s * HSTR + j] = f2bf(v1);
                float v2 = acc2[jt][r]; v2 = (v2 > 0.f) ? v2 : 0.01f * v2;
                Ht2[(s + 1) * HSTR + j] = f2bf(v2);
            }
        }
    }
    __syncthreads();

    // ---- stage 2: L1[256c][64s] (K=64), L2[256c][64s] (K=192) ----
    f32x4 l1[16], l2[16];
    #pragma unroll
    for (int ct = 0; ct < 16; ++ct) { l1[ct] = {0.f, 0.f, 0.f, 0.f}; l2[ct] = {0.f, 0.f, 0.f, 0.f}; }

    {
        const ushort* wb1 = ws + WB1_OFF + (size_t)p * 256 * 64;
        const ushort* wb2 = ws + WB2_OFF + (size_t)p * 256 * 192;
        const int koff = klane << 3;

        // branch 1: conv1x1, K = 64
        for (int kk = 0; kk < 2; ++kk) {
            const int h0 = kk * 32 + koff;
            const int srow = s0 + nlane;
            bf16x8 bfrag = *reinterpret_cast<const bf16x8*>(&Ht1[srow * HSTR + h0]);
            #pragma unroll
            for (int ct = 0; ct < 16; ++ct) {
                const int c = (ct << 4) + nlane;
                bf16x8 af = *reinterpret_cast<const bf16x8*>(&wb1[(size_t)c * 64 + h0]);
                l1[ct] = __builtin_amdgcn_mfma_f32_16x16x32_bf16(af, bfrag, l1[ct], 0, 0, 0);
            }
        }
        // branch 2: conv3, K = 192 (k2 = tap*64 + h)
        for (int kk = 0; kk < 6; ++kk) {
            const int tap = kk >> 1;
            const int h0 = ((kk & 1) << 5) + koff;
            const int row = s0 + nlane + tap;       // s' = s + tap - 1 -> row = s' + 1
            bf16x8 bfrag = *reinterpret_cast<const bf16x8*>(&Ht2[row * HSTR + h0]);
            const int ka = kk * 32 + koff;
            #pragma unroll
            for (int ct = 0; ct < 16; ++ct) {
                const int c = (ct << 4) + nlane;
                bf16x8 af = *reinterpret_cast<const bf16x8*>(&wb2[(size_t)c * 192 + ka]);
                l2[ct] = __builtin_amdgcn_mfma_f32_16x16x32_bf16(af, bfrag, l2[ct], 0, 0, 0);
            }
        }
    }

    // ---- epilogue: pools + gates + temporal max ----
    {
        const int s = s0 + nlane;
        #pragma unroll
        for (int ct = 0; ct < 16; ++ct) {
            #pragma unroll
            for (int r = 0; r < 4; ++r) {
                const int c = (ct << 4) + (klane << 2) + r;
                const float xm2 = bf2f(Xt[(s)     * XSTRIDE + c]);
                const float xm1 = bf2f(Xt[(s + 1) * XSTRIDE + c]);
                const float x0  = bf2f(Xt[(s + 2) * XSTRIDE + c]);
                const float xp1 = bf2f(Xt[(s + 3) * XSTRIDE + c]);
                const float xp2 = bf2f(Xt[(s + 4) * XSTRIDE + c]);
                const float avg3 = (xm1 + x0 + xp1) * (1.f / 3.f);
                const float avg5 = (xm2 + xm1 + x0 + xp1 + xp2) * 0.2f;
                float mx3 = x0;
                if (s > 0)  mx3 = fmaxf(mx3, xm1);
                if (s < 63) mx3 = fmaxf(mx3, xp1);
                float mx5 = mx3;
                if (s > 1)  mx5 = fmaxf(mx5, xm2);
                if (s < 62) mx5 = fmaxf(mx5, xp2);
                const float g1 = 1.f / (1.f + __expf(-l1[ct][r]));
                const float g2 = 1.f / (1.f + __expf(-l2[ct][r]));
                float m = (avg3 + mx3) * g1 + (avg5 + mx5) * g2;
                m = fmaxf(m, __shfl_xor(m, 1, 64));
                m = fmaxf(m, __shfl_xor(m, 2, 64));
                m = fmaxf(m, __shfl_xor(m, 4, 64));
                m = fmaxf(m, __shfl_xor(m, 8, 64));
                if (nlane == 0) pm[wid][c] = m;
            }
        }
    }
    __syncthreads();
    {
        const float m = fmaxf(fmaxf(pm[0][t], pm[1][t]), fmaxf(pm[2][t], pm[3][t]));
        out[(size_t)blk * CH_ + t] = m;
    }
}

// ================= fallback (round-2 fp32 kernel) if ws too small =================
#define HPAD 68
__global__ __launch_bounds__(256, 1) void tfa_fused_fp32(
    const float* __restrict__ x,
    const float* __restrict__ W1a,
    const float* __restrict__ W1b,
    const float* __restrict__ W2a,
    const float* __restrict__ W2b,
    float* __restrict__ out)
{
    __shared__ float xs[CH_ * SEQ_];
    __shared__ float h1s[HID_ * HPAD];
    __shared__ float h2s[HID_ * HPAD];

    const int blk = blockIdx.x;
    const int b = blk >> 4;
    const int p = blk & 15;
    const int t = threadIdx.x;
    const int lane = t & 63;
    const int wid = __builtin_amdgcn_readfirstlane(t >> 6);

    {
        const float* xb = x + (size_t)b * (SEQ_ * CH_ * PARTS_) + p;
        const int s = lane;
        for (int cc = wid; cc < CH_; cc += 4)
            xs[cc * SEQ_ + s] = xb[((size_t)s * CH_ + cc) * PARTS_];
    }
    __syncthreads();

    const int jj = lane & 15;
    const int sg = lane >> 4;
    const int sbase = sg << 4;
    const float fl = (sg > 0) ? 1.f : 0.f;
    const float fr = (sg < 3) ? 1.f : 0.f;
    const int il  = (sg > 0) ? -1 : 0;
    const int ir  = (sg < 3) ? 16 : 0;
    const int ir2 = (sg < 3) ? 17 : 0;
    const int il2 = (sg > 0) ? -2 : 0;

    {
        const int j0 = wid * 16 + jj;
        float a1[16], a2[16];
        #pragma unroll
        for (int i = 0; i < 16; ++i) { a1[i] = 0.f; a2[i] = 0.f; }
        const float* w1p = W1a + (size_t)(p * HID_ + j0) * (CH_ * 3);
        const float* w2p = W2a + (size_t)(p * HID_ + j0) * (CH_ * 3);
        #pragma unroll 4
        for (int c = 0; c < CH_; ++c) {
            const float* xrow = &xs[c * SEQ_ + sbase];
            float xv[18];
            {
                float4 q;
                q = *(const float4*)(xrow);      xv[1]=q.x; xv[2]=q.y; xv[3]=q.z; xv[4]=q.w;
                q = *(const float4*)(xrow + 4);  xv[5]=q.x; xv[6]=q.y; xv[7]=q.z; xv[8]=q.w;
                q = *(const float4*)(xrow + 8);  xv[9]=q.x; xv[10]=q.y; xv[11]=q.z; xv[12]=q.w;
                q = *(const float4*)(xrow + 12); xv[13]=q.x; xv[14]=q.y; xv[15]=q.z; xv[16]=q.w;
            }
            xv[0]  = xrow[il] * fl;
            xv[17] = xrow[ir] * fr;
            const float w10 = w1p[c*3+0], w11 = w1p[c*3+1], w12 = w1p[c*3+2];
            const float w20 = w2p[c*3+0], w21 = w2p[c*3+1], w22 = w2p[c*3+2];
            #pragma unroll
            for (int i = 0; i < 16; ++i) {
                a1[i] = fmaf(xv[i], w10, fmaf(xv[i+1], w11, fmaf(xv[i+2], w12, a1[i])));
                a2[i] = fmaf(xv[i], w20, fmaf(xv[i+1], w21, fmaf(xv[i+2], w22, a2[i])));
            }
        }
        float* h1w = &h1s[j0 * HPAD + sbase];
        float* h2w = &h2s[j0 * HPAD + sbase];
        #pragma unroll
        for (int q4 = 0; q4 < 4; ++q4) {
            float4 v1, v2; float u;
            u = a1[4*q4+0]; v1.x = (u>0.f)?u:0.01f*u;
            u = a1[4*q4+1]; v1.y = (u>0.f)?u:0.01f*u;
            u = a1[4*q4+2]; v1.z = (u>0.f)?u:0.01f*u;
            u = a1[4*q4+3]; v1.w = (u>0.f)?u:0.01f*u;
            u = a2[4*q4+0]; v2.x = (u>0.f)?u:0.01f*u;
            u = a2[4*q4+1]; v2.y = (u>0.f)?u:0.01f*u;
            u = a2[4*q4+2]; v2.z = (u>0.f)?u:0.01f*u;
            u = a2[4*q4+3]; v2.w = (u>0.f)?u:0.01f*u;
            *(float4*)(h1w + 4*q4) = v1;
            *(float4*)(h2w + 4*q4) = v2;
        }
    }
    __syncthreads();

    {
        const int cbase = wid * 64;
        float l1[4][16], l2[4][16];
        #pragma unroll
        for (int ch = 0; ch < 4; ++ch)
            #pragma unroll
            for (int i = 0; i < 16; ++i) { l1[ch][i] = 0.f; l2[ch][i] = 0.f; }
        #pragma unroll 2
        for (int h = 0; h < HID_; ++h) {
            const float* h1row = &h1s[h * HPAD + sbase];
            const float* h2row = &h2s[h * HPAD + sbase];
            float hv1[16], hv2[18];
            {
                float4 q;
                q = *(const float4*)(h1row);      hv1[0]=q.x; hv1[1]=q.y; hv1[2]=q.z; hv1[3]=q.w;
                q = *(const float4*)(h1row + 4);  hv1[4]=q.x; hv1[5]=q.y; hv1[6]=q.z; hv1[7]=q.w;
                q = *(const float4*)(h1row + 8);  hv1[8]=q.x; hv1[9]=q.y; hv1[10]=q.z; hv1[11]=q.w;
                q = *(const float4*)(h1row + 12); hv1[12]=q.x; hv1[13]=q.y; hv1[14]=q.z; hv1[15]=q.w;
                q = *(const float4*)(h2row);      hv2[1]=q.x; hv2[2]=q.y; hv2[3]=q.z; hv2[4]=q.w;
                q = *(const float4*)(h2row + 4);  hv2[5]=q.x; hv2[6]=q.y; hv2[7]=q.z; hv2[8]=q.w;
                q = *(const float4*)(h2row + 8);  hv2[9]=q.x; hv2[10]=q.y; hv2[11]=q.z; hv2[12]=q.w;
                q = *(const float4*)(h2row + 12); hv2[13]=q.x; hv2[14]=q.y; hv2[15]=q.z; hv2[16]=q.w;
            }
            hv2[0]  = h2row[il] * fl;
            hv2[17] = h2row[ir] * fr;
            #pragma unroll
            for (int ch = 0; ch < 4; ++ch) {
                const int c = cbase + ch * 16 + jj;
                const float wb1 = W1b[((size_t)p * CH_ + c) * HID_ + h];
                const float* w2q = W2b + ((size_t)(p * CH_ + c) * HID_ + h) * 3;
                const float wa = w2q[0], wb = w2q[1], wc = w2q[2];
                #pragma unroll
                for (int i = 0; i < 16; ++i) {
                    l1[ch][i] = fmaf(hv1[i], wb1, l1[ch][i]);
                    l2[ch][i] = fmaf(hv2[i], wa, fmaf(hv2[i+1], wb, fmaf(hv2[i+2], wc, l2[ch][i])));
                }
            }
        }
        #pragma unroll
        for (int ch = 0; ch < 4; ++ch) {
            const int c = cbase + ch * 16 + jj;
            const float* xrow = &xs[c * SEQ_ + sbase];
            float xp[20];
            {
                float4 q;
                q = *(const float4*)(xrow);      xp[2]=q.x; xp[3]=q.y; xp[4]=q.z; xp[5]=q.w;
                q = *(const float4*)(xrow + 4);  xp[6]=q.x; xp[7]=q.y; xp[8]=q.z; xp[9]=q.w;
                q = *(const float4*)(xrow + 8);  xp[10]=q.x; xp[11]=q.y; xp[12]=q.z; xp[13]=q.w;
                q = *(const float4*)(xrow + 12); xp[14]=q.x; xp[15]=q.y; xp[16]=q.z; xp[17]=q.w;
            }
            xp[0]  = xrow[il2] * fl;
            xp[1]  = xrow[il]  * fl;
            xp[18] = xrow[ir]  * fr;
            xp[19] = xrow[ir2] * fr;
            float mloc = -INFINITY;
            #pragma unroll
            for (int i = 0; i < 16; ++i) {
                const int s = sbase + i;
                const float x0  = xp[i+2];
                const float am1 = xp[i+1], ap1 = xp[i+3];
                const float am2 = xp[i],   ap2 = xp[i+4];
                const float avg3 = (am1 + x0 + ap1) * (1.f / 3.f);
                const float avg5 = (am2 + am1 + x0 + ap1 + ap2) * 0.2f;
                float mx3 = x0;
                if (s > 0)  mx3 = fmaxf(mx3, am1);
                if (s < 63) mx3 = fmaxf(mx3, ap1);
                float mx5 = mx3;
                if (s > 1)  mx5 = fmaxf(mx5, am2);
                if (s < 62) mx5 = fmaxf(mx5, ap2);
                const float g1 = 1.f / (1.f + __expf(-l1[ch][i]));
                const float g2 = 1.f / (1.f + __expf(-l2[ch][i]));
                const float m = (avg3 + mx3) * g1 + (avg5 + mx5) * g2;
                mloc = fmaxf(mloc, m);
            }
            mloc = fmaxf(mloc, __shfl_xor(mloc, 16, 64));
            mloc = fmaxf(mloc, __shfl_xor(mloc, 32, 64));
            if (sg == 0)
                out[(size_t)blk * CH_ + c] = mloc;
        }
    }
}

extern "C" void kernel_launch(void* const* d_in, const int* in_sizes, int n_in,
                              void* d_out, int out_size, void* d_ws, size_t ws_size,
                              hipStream_t stream) {
    const float* x   = (const float*)d_in[0];
    const float* W1a = (const float*)d_in[1];
    const float* W1b = (const float*)d_in[2];
    const float* W2a = (const float*)d_in[3];
    const float* W2b = (const float*)d_in[4];
    float* out = (float*)d_out;

    if (ws_size >= WS_BYTES) {
        ushort* ws = (ushort*)d_ws;
        const int total = WS_ELEMS - 16 * 64 * 768;  // threads: NA covers Wa1+Wa2 together
        const int nthreads = 16 * 64 * 768 + 16 * 256 * 64 + 16 * 256 * 192;
        prep_weights<<<dim3((nthreads + 255) / 256), dim3(256), 0, stream>>>(W1a, W1b, W2a, W2b, ws);
        tfa_mfma<<<dim3(B_ * PARTS_), dim3(256), 0, stream>>>(x, ws, out);
        (void)total;
    } else {
        tfa_fused_fp32<<<dim3(B_ * PARTS_), dim3(256), 0, stream>>>(x, W1a, W1b, W2a, W2b, out);
    }
}

// Round 4
// 582.097 us; speedup vs baseline: 10.8245x; 1.0571x over previous
//
#include <hip/hip_runtime.h>
#include <hip/hip_bf16.h>
#include <math.h>

#define B_ 128
#define SEQ_ 64
#define CH_ 256
#define PARTS_ 16
#define HID_ 64

typedef __attribute__((ext_vector_type(8))) short bf16x8;
typedef __attribute__((ext_vector_type(4))) float f32x4;

// ---- ws layout (bf16 elements) ----
// Wa1[p][j][k1], k1 = tap*256 + c   : 16*64*768
// Wa2[p][j][k1]                     : 16*64*768
// Wb1[p][c][h]                      : 16*256*64
// Wb2[p][c][k2], k2 = tap*64 + h    : 16*256*192
// xT[b][p][s][c]                    : 128*16*64*256   (optional, if ws big enough)
#define WA1_OFF 0
#define WA2_OFF (16 * 64 * 768)
#define WB1_OFF (2 * 16 * 64 * 768)
#define WB2_OFF (2 * 16 * 64 * 768 + 16 * 256 * 64)
#define WS_ELEMS (2 * 16 * 64 * 768 + 16 * 256 * 64 + 16 * 256 * 192)
#define WS_BYTES ((size_t)WS_ELEMS * 2)
#define XT_ELEMS ((size_t)B_ * PARTS_ * SEQ_ * CH_)
#define WS_FULL_BYTES (WS_BYTES + XT_ELEMS * 2)

__device__ __forceinline__ ushort f2bf(float f) {
    __hip_bfloat16 h = __float2bfloat16(f);
    return *reinterpret_cast<ushort*>(&h);
}
__device__ __forceinline__ float bf2f(ushort u) {
    __hip_bfloat16 h;
    *reinterpret_cast<ushort*>(&h) = u;
    return __bfloat162float(h);
}

// ================= pre-pass A: reorder weights to bf16 MFMA-A layouts =================
__global__ __launch_bounds__(256) void prep_weights(
    const float* __restrict__ W1a, const float* __restrict__ W1b,
    const float* __restrict__ W2a, const float* __restrict__ W2b,
    ushort* __restrict__ ws)
{
    const int NA  = 16 * 64 * 768;
    const int NB1 = 16 * 256 * 64;
    const int NB2 = 16 * 256 * 192;
    int idx = blockIdx.x * 256 + threadIdx.x;
    if (idx < NA) {
        int k = idx % 768, j = (idx / 768) % 64, p = idx / (768 * 64);
        int tap = k >> 8, c = k & 255;
        size_t src = ((size_t)(p * 64 + j) * 256 + c) * 3 + tap;
        ws[WA1_OFF + idx] = f2bf(W1a[src]);
        ws[WA2_OFF + idx] = f2bf(W2a[src]);
    } else if (idx < NA + NB1) {
        int i2 = idx - NA;
        ws[WB1_OFF + i2] = f2bf(W1b[i2]);   // already [p][c][h]
    } else if (idx < NA + NB1 + NB2) {
        int i2 = idx - NA - NB1;            // over [p][c][k2]
        int k = i2 % 192, c = (i2 / 192) % 256, p = i2 / (192 * 256);
        int tap = k / 64, h = k & 63;
        ws[WB2_OFF + i2] = f2bf(W2b[((size_t)(p * 256 + c) * 64 + h) * 3 + tap]);
    }
}

// ================= pre-pass B: coalesced transpose x -> xT[b][p][s][c] bf16 ==========
// block = (b, s); thread t: p = t>>4, c-block = t&15. Reads are L1-local within the
// 16 KB (s)-row; writes are 32 B contiguous per thread, 512 B per p-row (coalesced).
__global__ __launch_bounds__(256) void prep_x(
    const float* __restrict__ x, ushort* __restrict__ xT)
{
    const int idx = blockIdx.x;
    const int b = idx >> 6, s = idx & 63;
    const int t = threadIdx.x;
    const int p = t >> 4, cb = t & 15;
    const float* src = x + (((size_t)(b * 64 + s)) * 256 + cb * 16) * 16 + p;
    bf16x8 v0, v1;
    #pragma unroll
    for (int i = 0; i < 8; ++i)  v0[i] = (short)f2bf(src[i * 16]);
    #pragma unroll
    for (int i = 0; i < 8; ++i)  v1[i] = (short)f2bf(src[(i + 8) * 16]);
    ushort* dst = xT + (((size_t)(b * 16 + p)) * 64 + s) * 256 + cb * 16;
    *reinterpret_cast<bf16x8*>(dst)     = v0;
    *reinterpret_cast<bf16x8*>(dst + 8) = v1;
}

// ================= main fused kernel (MFMA path) =================
#define XSTRIDE 264   // bf16 elems per Xt row (256 + 8 pad)
#define XROWS   68    // rows = s' + 2, s' in [-2, 65]; rows 0,1,66,67 zero
#define HSTR    72    // bf16 elems per Ht row (64 + 8 pad)

__global__ __launch_bounds__(256, 2) void tfa_mfma(
    const float* __restrict__ x,
    const ushort* __restrict__ ws,
    const ushort* __restrict__ xT,     // may be null -> slow gather
    float* __restrict__ out)
{
    __shared__ __align__(16) ushort Xt[XROWS * XSTRIDE];      // 35.9 KB
    __shared__ __align__(16) ushort Ht1[64 * HSTR];           // 9.2 KB  row = s
    __shared__ __align__(16) ushort Ht2[66 * HSTR];           // 9.5 KB  row = s'+1
    __shared__ float pm[4][CH_];                              // 4 KB

    // XCD-aware mapping: XCD (= blockIdx%8, heuristic) gets p in {2*xcd, 2*xcd+1}
    // so its L2 working set of ws is ~656 KB (fits 4 MB).
    const int i = blockIdx.x;
    const int xcd = i & 7;
    const int k = i >> 3;
    const int p = (xcd << 1) | (k & 1);
    const int b = k >> 1;
    const int lblk = b * PARTS_ + p;    // logical block for output indexing

    const int t = threadIdx.x;
    const int lane = t & 63;
    const int wid = __builtin_amdgcn_readfirstlane(t >> 6);   // wave id = s-tile
    const int nlane = lane & 15;                              // N index within tile
    const int klane = lane >> 4;                              // k-group
    const int s0 = wid << 4;

    // ---- zero pad rows ----
    for (int q = t; q < 2 * XSTRIDE; q += 256) {
        Xt[q] = 0;                          // rows 0,1
        Xt[66 * XSTRIDE + q] = 0;           // rows 66,67
    }
    for (int q = t; q < HSTR; q += 256) {
        Ht2[q] = 0;                         // row 0
        Ht2[65 * HSTR + q] = 0;             // row 65
    }

    // ---- stage x slice into Xt[s+2][c] ----
    if (xT) {
        const ushort* xb = xT + ((size_t)lblk * SEQ_) * CH_;
        const int half = lane >> 5;          // 0/1
        const int col8 = (lane & 31) * 8;    // 16 B per lane
        #pragma unroll
        for (int kk = 0; kk < 8; ++kk) {
            const int row = kk * 8 + wid * 2 + half;
            bf16x8 v = *reinterpret_cast<const bf16x8*>(xb + (size_t)row * CH_ + col8);
            *reinterpret_cast<bf16x8*>(&Xt[(row + 2) * XSTRIDE + col8]) = v;
        }
    } else {
        const float* xb = x + (size_t)b * (SEQ_ * CH_ * PARTS_) + p;
        for (int cc = wid; cc < CH_; cc += 4) {
            float v = xb[((size_t)lane * CH_ + cc) * PARTS_];
            Xt[(lane + 2) * XSTRIDE + cc] = f2bf(v);
        }
    }
    __syncthreads();

    // ---- stage 1: H[64j][64s] = Wa . im2col(X), two branches; wave owns s-tile ----
    {
        f32x4 acc1[4], acc2[4];
        #pragma unroll
        for (int jt = 0; jt < 4; ++jt) { acc1[jt] = {0.f, 0.f, 0.f, 0.f}; acc2[jt] = {0.f, 0.f, 0.f, 0.f}; }

        const ushort* wa1 = ws + WA1_OFF + (size_t)p * 64 * 768;
        const ushort* wa2 = ws + WA2_OFF + (size_t)p * 64 * 768;
        const int koff = klane << 3;

        #pragma unroll 2
        for (int kk = 0; kk < 24; ++kk) {
            const int tap = kk >> 3;
            const int c0 = ((kk & 7) << 5) + koff;
            const int row = s0 + nlane + tap + 1;   // s' = s + tap - 1 -> row = s' + 2
            bf16x8 bfrag = *reinterpret_cast<const bf16x8*>(&Xt[row * XSTRIDE + c0]);
            const int ka = kk * 32 + koff;
            #pragma unroll
            for (int jt = 0; jt < 4; ++jt) {
                const int j = (jt << 4) + nlane;
                bf16x8 a1 = *reinterpret_cast<const bf16x8*>(&wa1[(size_t)j * 768 + ka]);
                acc1[jt] = __builtin_amdgcn_mfma_f32_16x16x32_bf16(a1, bfrag, acc1[jt], 0, 0, 0);
                bf16x8 a2 = *reinterpret_cast<const bf16x8*>(&wa2[(size_t)j * 768 + ka]);
                acc2[jt] = __builtin_amdgcn_mfma_f32_16x16x32_bf16(a2, bfrag, acc2[jt], 0, 0, 0);
            }
        }

        // LeakyReLU -> bf16 -> Ht   (D: row j = jt*16 + klane*4 + r, col s = s0 + nlane)
        const int s = s0 + nlane;
        #pragma unroll
        for (int jt = 0; jt < 4; ++jt) {
            #pragma unroll
            for (int r = 0; r < 4; ++r) {
                const int j = (jt << 4) + (klane << 2) + r;
                float v1 = acc1[jt][r]; v1 = (v1 > 0.f) ? v1 : 0.01f * v1;
                Ht1[s * HSTR + j] = f2bf(v1);
                float v2 = acc2[jt][r]; v2 = (v2 > 0.f) ? v2 : 0.01f * v2;
                Ht2[(s + 1) * HSTR + j] = f2bf(v2);
            }
        }
    }
    __syncthreads();

    // ---- stage 2: L1[256c][64s] (K=64), L2[256c][64s] (K=192) ----
    f32x4 l1[16], l2[16];
    #pragma unroll
    for (int ct = 0; ct < 16; ++ct) { l1[ct] = {0.f, 0.f, 0.f, 0.f}; l2[ct] = {0.f, 0.f, 0.f, 0.f}; }

    {
        const ushort* wb1 = ws + WB1_OFF + (size_t)p * 256 * 64;
        const ushort* wb2 = ws + WB2_OFF + (size_t)p * 256 * 192;
        const int koff = klane << 3;

        // branch 1: conv1x1, K = 64
        #pragma unroll
        for (int kk = 0; kk < 2; ++kk) {
            const int h0 = kk * 32 + koff;
            const int srow = s0 + nlane;
            bf16x8 bfrag = *reinterpret_cast<const bf16x8*>(&Ht1[srow * HSTR + h0]);
            #pragma unroll
            for (int ct = 0; ct < 16; ++ct) {
                const int c = (ct << 4) + nlane;
                bf16x8 af = *reinterpret_cast<const bf16x8*>(&wb1[(size_t)c * 64 + h0]);
                l1[ct] = __builtin_amdgcn_mfma_f32_16x16x32_bf16(af, bfrag, l1[ct], 0, 0, 0);
            }
        }
        // branch 2: conv3, K = 192 (k2 = tap*64 + h)
        #pragma unroll 2
        for (int kk = 0; kk < 6; ++kk) {
            const int tap = kk >> 1;
            const int h0 = ((kk & 1) << 5) + koff;
            const int row = s0 + nlane + tap;       // s' = s + tap - 1 -> row = s' + 1
            bf16x8 bfrag = *reinterpret_cast<const bf16x8*>(&Ht2[row * HSTR + h0]);
            const int ka = kk * 32 + koff;
            #pragma unroll
            for (int ct = 0; ct < 16; ++ct) {
                const int c = (ct << 4) + nlane;
                bf16x8 af = *reinterpret_cast<const bf16x8*>(&wb2[(size_t)c * 192 + ka]);
                l2[ct] = __builtin_amdgcn_mfma_f32_16x16x32_bf16(af, bfrag, l2[ct], 0, 0, 0);
            }
        }
    }

    // ---- epilogue: pools + gates + temporal max ----
    {
        const int s = s0 + nlane;
        #pragma unroll
        for (int ct = 0; ct < 16; ++ct) {
            #pragma unroll
            for (int r = 0; r < 4; ++r) {
                const int c = (ct << 4) + (klane << 2) + r;
                const float xm2 = bf2f(Xt[(s)     * XSTRIDE + c]);
                const float xm1 = bf2f(Xt[(s + 1) * XSTRIDE + c]);
                const float x0  = bf2f(Xt[(s + 2) * XSTRIDE + c]);
                const float xp1 = bf2f(Xt[(s + 3) * XSTRIDE + c]);
                const float xp2 = bf2f(Xt[(s + 4) * XSTRIDE + c]);
                const float avg3 = (xm1 + x0 + xp1) * (1.f / 3.f);
                const float avg5 = (xm2 + xm1 + x0 + xp1 + xp2) * 0.2f;
                float mx3 = x0;
                if (s > 0)  mx3 = fmaxf(mx3, xm1);
                if (s < 63) mx3 = fmaxf(mx3, xp1);
                float mx5 = mx3;
                if (s > 1)  mx5 = fmaxf(mx5, xm2);
                if (s < 62) mx5 = fmaxf(mx5, xp2);
                const float g1 = 1.f / (1.f + __expf(-l1[ct][r]));
                const float g2 = 1.f / (1.f + __expf(-l2[ct][r]));
                float m = (avg3 + mx3) * g1 + (avg5 + mx5) * g2;
                m = fmaxf(m, __shfl_xor(m, 1, 64));
                m = fmaxf(m, __shfl_xor(m, 2, 64));
                m = fmaxf(m, __shfl_xor(m, 4, 64));
                m = fmaxf(m, __shfl_xor(m, 8, 64));
                if (nlane == 0) pm[wid][c] = m;
            }
        }
    }
    __syncthreads();
    {
        const float m = fmaxf(fmaxf(pm[0][t], pm[1][t]), fmaxf(pm[2][t], pm[3][t]));
        out[(size_t)lblk * CH_ + t] = m;
    }
}

// ================= fallback (round-2 fp32 kernel) if ws too small =================
#define HPAD 68
__global__ __launch_bounds__(256, 1) void tfa_fused_fp32(
    const float* __restrict__ x,
    const float* __restrict__ W1a,
    const float* __restrict__ W1b,
    const float* __restrict__ W2a,
    const float* __restrict__ W2b,
    float* __restrict__ out)
{
    __shared__ float xs[CH_ * SEQ_];
    __shared__ float h1s[HID_ * HPAD];
    __shared__ float h2s[HID_ * HPAD];

    const int blk = blockIdx.x;
    const int b = blk >> 4;
    const int p = blk & 15;
    const int t = threadIdx.x;
    const int lane = t & 63;
    const int wid = __builtin_amdgcn_readfirstlane(t >> 6);

    {
        const float* xb = x + (size_t)b * (SEQ_ * CH_ * PARTS_) + p;
        const int s = lane;
        for (int cc = wid; cc < CH_; cc += 4)
            xs[cc * SEQ_ + s] = xb[((size_t)s * CH_ + cc) * PARTS_];
    }
    __syncthreads();

    const int jj = lane & 15;
    const int sg = lane >> 4;
    const int sbase = sg << 4;
    const float fl = (sg > 0) ? 1.f : 0.f;
    const float fr = (sg < 3) ? 1.f : 0.f;
    const int il  = (sg > 0) ? -1 : 0;
    const int ir  = (sg < 3) ? 16 : 0;
    const int ir2 = (sg < 3) ? 17 : 0;
    const int il2 = (sg > 0) ? -2 : 0;

    {
        const int j0 = wid * 16 + jj;
        float a1[16], a2[16];
        #pragma unroll
        for (int q = 0; q < 16; ++q) { a1[q] = 0.f; a2[q] = 0.f; }
        const float* w1p = W1a + (size_t)(p * HID_ + j0) * (CH_ * 3);
        const float* w2p = W2a + (size_t)(p * HID_ + j0) * (CH_ * 3);
        #pragma unroll 4
        for (int c = 0; c < CH_; ++c) {
            const float* xrow = &xs[c * SEQ_ + sbase];
            float xv[18];
            {
                float4 q;
                q = *(const float4*)(xrow);      xv[1]=q.x; xv[2]=q.y; xv[3]=q.z; xv[4]=q.w;
                q = *(const float4*)(xrow + 4);  xv[5]=q.x; xv[6]=q.y; xv[7]=q.z; xv[8]=q.w;
                q = *(const float4*)(xrow + 8);  xv[9]=q.x; xv[10]=q.y; xv[11]=q.z; xv[12]=q.w;
                q = *(const float4*)(xrow + 12); xv[13]=q.x; xv[14]=q.y; xv[15]=q.z; xv[16]=q.w;
            }
            xv[0]  = xrow[il] * fl;
            xv[17] = xrow[ir] * fr;
            const float w10 = w1p[c*3+0], w11 = w1p[c*3+1], w12 = w1p[c*3+2];
            const float w20 = w2p[c*3+0], w21 = w2p[c*3+1], w22 = w2p[c*3+2];
            #pragma unroll
            for (int q = 0; q < 16; ++q) {
                a1[q] = fmaf(xv[q], w10, fmaf(xv[q+1], w11, fmaf(xv[q+2], w12, a1[q])));
                a2[q] = fmaf(xv[q], w20, fmaf(xv[q+1], w21, fmaf(xv[q+2], w22, a2[q])));
            }
        }
        float* h1w = &h1s[j0 * HPAD + sbase];
        float* h2w = &h2s[j0 * HPAD + sbase];
        #pragma unroll
        for (int q4 = 0; q4 < 4; ++q4) {
            float4 v1, v2; float u;
            u = a1[4*q4+0]; v1.x = (u>0.f)?u:0.01f*u;
            u = a1[4*q4+1]; v1.y = (u>0.f)?u:0.01f*u;
            u = a1[4*q4+2]; v1.z = (u>0.f)?u:0.01f*u;
            u = a1[4*q4+3]; v1.w = (u>0.f)?u:0.01f*u;
            u = a2[4*q4+0]; v2.x = (u>0.f)?u:0.01f*u;
            u = a2[4*q4+1]; v2.y = (u>0.f)?u:0.01f*u;
            u = a2[4*q4+2]; v2.z = (u>0.f)?u:0.01f*u;
            u = a2[4*q4+3]; v2.w = (u>0.f)?u:0.01f*u;
            *(float4*)(h1w + 4*q4) = v1;
            *(float4*)(h2w + 4*q4) = v2;
        }
    }
    __syncthreads();

    {
        const int cbase = wid * 64;
        float l1[4][16], l2[4][16];
        #pragma unroll
        for (int ch = 0; ch < 4; ++ch)
            #pragma unroll
            for (int q = 0; q < 16; ++q) { l1[ch][q] = 0.f; l2[ch][q] = 0.f; }
        #pragma unroll 2
        for (int h = 0; h < HID_; ++h) {
            const float* h1row = &h1s[h * HPAD + sbase];
            const float* h2row = &h2s[h * HPAD + sbase];
            float hv1[16], hv2[18];
            {
                float4 q;
                q = *(const float4*)(h1row);      hv1[0]=q.x; hv1[1]=q.y; hv1[2]=q.z; hv1[3]=q.w;
                q = *(const float4*)(h1row + 4);  hv1[4]=q.x; hv1[5]=q.y; hv1[6]=q.z; hv1[7]=q.w;
                q = *(const float4*)(h1row + 8);  hv1[8]=q.x; hv1[9]=q.y; hv1[10]=q.z; hv1[11]=q.w;
                q = *(const float4*)(h1row + 12); hv1[12]=q.x; hv1[13]=q.y; hv1[14]=q.z; hv1[15]=q.w;
                q = *(const float4*)(h2row);      hv2[1]=q.x; hv2[2]=q.y; hv2[3]=q.z; hv2[4]=q.w;
                q = *(const float4*)(h2row + 4);  hv2[5]=q.x; hv2[6]=q.y; hv2[7]=q.z; hv2[8]=q.w;
                q = *(const float4*)(h2row + 8);  hv2[9]=q.x; hv2[10]=q.y; hv2[11]=q.z; hv2[12]=q.w;
                q = *(const float4*)(h2row + 12); hv2[13]=q.x; hv2[14]=q.y; hv2[15]=q.z; hv2[16]=q.w;
            }
            hv2[0]  = h2row[il] * fl;
            hv2[17] = h2row[ir] * fr;
            #pragma unroll
            for (int ch = 0; ch < 4; ++ch) {
                const int c = cbase + ch * 16 + jj;
                const float wb1 = W1b[((size_t)p * CH_ + c) * HID_ + h];
                const float* w2q = W2b + ((size_t)(p * CH_ + c) * HID_ + h) * 3;
                const float wa = w2q[0], wb = w2q[1], wc = w2q[2];
                #pragma unroll
                for (int q = 0; q < 16; ++q) {
                    l1[ch][q] = fmaf(hv1[q], wb1, l1[ch][q]);
                    l2[ch][q] = fmaf(hv2[q], wa, fmaf(hv2[q+1], wb, fmaf(hv2[q+2], wc, l2[ch][q])));
                }
            }
        }
        #pragma unroll
        for (int ch = 0; ch < 4; ++ch) {
            const int c = cbase + ch * 16 + jj;
            const float* xrow = &xs[c * SEQ_ + sbase];
            float xp[20];
            {
                float4 q;
                q = *(const float4*)(xrow);      xp[2]=q.x; xp[3]=q.y; xp[4]=q.z; xp[5]=q.w;
                q = *(const float4*)(xrow + 4);  xp[6]=q.x; xp[7]=q.y; xp[8]=q.z; xp[9]=q.w;
                q = *(const float4*)(xrow + 8);  xp[10]=q.x; xp[11]=q.y; xp[12]=q.z; xp[13]=q.w;
                q = *(const float4*)(xrow + 12); xp[14]=q.x; xp[15]=q.y; xp[16]=q.z; xp[17]=q.w;
            }
            xp[0]  = xrow[il2] * fl;
            xp[1]  = xrow[il]  * fl;
            xp[18] = xrow[ir]  * fr;
            xp[19] = xrow[ir2] * fr;
            float mloc = -INFINITY;
            #pragma unroll
            for (int q = 0; q < 16; ++q) {
                const int s = sbase + q;
                const float x0  = xp[q+2];
                const float am1 = xp[q+1], ap1 = xp[q+3];
                const float am2 = xp[q],   ap2 = xp[q+4];
                const float avg3 = (am1 + x0 + ap1) * (1.f / 3.f);
                const float avg5 = (am2 + am1 + x0 + ap1 + ap2) * 0.2f;
                float mx3 = x0;
                if (s > 0)  mx3 = fmaxf(mx3, am1);
                if (s < 63) mx3 = fmaxf(mx3, ap1);
                float mx5 = mx3;
                if (s > 1)  mx5 = fmaxf(mx5, am2);
                if (s < 62) mx5 = fmaxf(mx5, ap2);
                const float g1 = 1.f / (1.f + __expf(-l1[ch][q]));
                const float g2 = 1.f / (1.f + __expf(-l2[ch][q]));
                const float m = (avg3 + mx3) * g1 + (avg5 + mx5) * g2;
                mloc = fmaxf(mloc, m);
            }
            mloc = fmaxf(mloc, __shfl_xor(mloc, 16, 64));
            mloc = fmaxf(mloc, __shfl_xor(mloc, 32, 64));
            if (sg == 0)
                out[(size_t)blk * CH_ + c] = mloc;
        }
    }
}

extern "C" void kernel_launch(void* const* d_in, const int* in_sizes, int n_in,
                              void* d_out, int out_size, void* d_ws, size_t ws_size,
                              hipStream_t stream) {
    const float* x   = (const float*)d_in[0];
    const float* W1a = (const float*)d_in[1];
    const float* W1b = (const float*)d_in[2];
    const float* W2a = (const float*)d_in[3];
    const float* W2b = (const float*)d_in[4];
    float* out = (float*)d_out;

    if (ws_size >= WS_BYTES) {
        ushort* ws = (ushort*)d_ws;
        const int nthreads = 16 * 64 * 768 + 16 * 256 * 64 + 16 * 256 * 192;
        prep_weights<<<dim3((nthreads + 255) / 256), dim3(256), 0, stream>>>(W1a, W1b, W2a, W2b, ws);
        ushort* xT = nullptr;
        if (ws_size >= WS_FULL_BYTES) {
            xT = ws + WS_ELEMS;
            prep_x<<<dim3(B_ * SEQ_), dim3(256), 0, stream>>>(x, xT);
        }
        tfa_mfma<<<dim3(B_ * PARTS_), dim3(256), 0, stream>>>(x, ws, xT, out);
    } else {
        tfa_fused_fp32<<<dim3(B_ * PARTS_), dim3(256), 0, stream>>>(x, W1a, W1b, W2a, W2b, out);
    }
}

// Round 5
// 365.786 us; speedup vs baseline: 17.2257x; 1.5914x over previous
//
#include <hip/hip_runtime.h>
#include <hip/hip_bf16.h>
#include <math.h>

#define B_ 128
#define SEQ_ 64
#define CH_ 256
#define PARTS_ 16
#define HID_ 64

typedef __attribute__((ext_vector_type(8))) short bf16x8;
typedef __attribute__((ext_vector_type(4))) float f32x4;

// ---- ws layout (bf16 elements), fragment-major: [p][kchunk][row][8] ----
// Wa1f/Wa2f: p, kc=96 (k1 = kc*8+e, k1 = tap*256 + c), j=64, e=8   : 786432 each
// Wb1f:      p, kc=8  (h  = kc*8+e),                   c=256, e=8  : 262144
// Wb2f:      p, kc=24 (k2 = kc*8+e, k2 = tap*64 + h),  c=256, e=8  : 786432
#define WA1_OFF 0
#define WA2_OFF (16 * 96 * 64 * 8)
#define WB1_OFF (2 * 16 * 96 * 64 * 8)
#define WB2_OFF (2 * 16 * 96 * 64 * 8 + 16 * 8 * 256 * 8)
#define WS_ELEMS (2 * 16 * 96 * 64 * 8 + 16 * 8 * 256 * 8 + 16 * 24 * 256 * 8)
#define WS_BYTES ((size_t)WS_ELEMS * 2)
#define XT_ELEMS ((size_t)B_ * PARTS_ * SEQ_ * CH_)
#define WS_FULL_BYTES (WS_BYTES + XT_ELEMS * 2)

__device__ __forceinline__ ushort f2bf(float f) {
    __hip_bfloat16 h = __float2bfloat16(f);
    return *reinterpret_cast<ushort*>(&h);
}
__device__ __forceinline__ float bf2f(ushort u) {
    __hip_bfloat16 h;
    *reinterpret_cast<ushort*>(&h) = u;
    return __bfloat162float(h);
}

// ========== pre-pass A: weights -> bf16 fragment-major layouts ==========
__global__ __launch_bounds__(256) void prep_weights(
    const float* __restrict__ W1a, const float* __restrict__ W1b,
    const float* __restrict__ W2a, const float* __restrict__ W2b,
    ushort* __restrict__ ws)
{
    const int NA  = 16 * 96 * 64 * 8;    // per array
    const int NB1 = 16 * 8 * 256 * 8;
    const int NB2 = 16 * 24 * 256 * 8;
    int idx = blockIdx.x * 256 + threadIdx.x;
    if (idx < NA) {
        // Wa1f/Wa2f: idx = ((p*96 + kc)*64 + j)*8 + e
        int e = idx & 7, j = (idx >> 3) & 63;
        int q = idx >> 9;                  // p*96 + kc
        int kc = q % 96, p = q / 96;
        int k1 = kc * 8 + e, tap = k1 >> 8, c = k1 & 255;
        size_t src = ((size_t)(p * 64 + j) * 256 + c) * 3 + tap;
        ws[WA1_OFF + idx] = f2bf(W1a[src]);
        ws[WA2_OFF + idx] = f2bf(W2a[src]);
    } else if (idx < NA + NB1) {
        int i2 = idx - NA;                 // ((p*8 + kc)*256 + c)*8 + e
        int e = i2 & 7, c = (i2 >> 3) & 255;
        int q = i2 >> 11;
        int kc = q & 7, p = q >> 3;
        int h = kc * 8 + e;
        ws[WB1_OFF + i2] = f2bf(W1b[((size_t)(p * 256 + c)) * 64 + h]);
    } else if (idx < NA + NB1 + NB2) {
        int i2 = idx - NA - NB1;           // ((p*24 + kc)*256 + c)*8 + e
        int e = i2 & 7, c = (i2 >> 3) & 255;
        int q = i2 >> 11;
        int kc = q % 24, p = q / 24;
        int k2 = kc * 8 + e, tap = k2 >> 6, h = k2 & 63;
        ws[WB2_OFF + i2] = f2bf(W2b[(((size_t)(p * 256 + c)) * 64 + h) * 3 + tap]);
    }
}

// ========== pre-pass B: LDS-staged transpose x -> xT[b][p][s][c] bf16 ==========
#define TSTR 264
__global__ __launch_bounds__(256) void prep_x(
    const float* __restrict__ x, ushort* __restrict__ xT)
{
    __shared__ ushort tile[PARTS_ * TSTR];   // [p][c], 8448 B
    const int b = blockIdx.x >> 6, s = blockIdx.x & 63;
    const float* src = x + ((size_t)(b * 64 + s)) * (CH_ * PARTS_);
    const int t = threadIdx.x;
    #pragma unroll
    for (int i = 0; i < 4; ++i) {
        int idx = t + i * 256;                        // float4 index over [c][p]
        float4 v = reinterpret_cast<const float4*>(src)[idx];
        int c = idx >> 2, p0 = (idx & 3) << 2;
        tile[(p0 + 0) * TSTR + c] = f2bf(v.x);
        tile[(p0 + 1) * TSTR + c] = f2bf(v.y);
        tile[(p0 + 2) * TSTR + c] = f2bf(v.z);
        tile[(p0 + 3) * TSTR + c] = f2bf(v.w);
    }
    __syncthreads();
    const int p = t >> 4, cb = t & 15;
    bf16x8 v0 = *reinterpret_cast<const bf16x8*>(&tile[p * TSTR + cb * 16]);
    bf16x8 v1 = *reinterpret_cast<const bf16x8*>(&tile[p * TSTR + cb * 16 + 8]);
    ushort* dst = xT + (((size_t)(b * 16 + p)) * 64 + s) * 256 + cb * 16;
    *reinterpret_cast<bf16x8*>(dst)     = v0;
    *reinterpret_cast<bf16x8*>(dst + 8) = v1;
}

// ========== main fused kernel ==========
#define XSTRIDE 264   // ushorts/row (16-B aligned rows)
#define XROWS   66    // row = s + 1; rows 0 and 65 are zero
#define HSTR    72    // ushorts/row for Ht1/Ht2 (16-B aligned)

__global__ __launch_bounds__(256, 3) void tfa_mfma(
    const float* __restrict__ x,
    const ushort* __restrict__ ws,
    const ushort* __restrict__ xT,
    float* __restrict__ out)
{
    __shared__ __align__(16) ushort Xt[XROWS * XSTRIDE];   // 34848 B
    __shared__ __align__(16) ushort Ht1[64 * HSTR];        // 9216 B  row = s
    __shared__ __align__(16) ushort Ht2[66 * HSTR];        // 9504 B  row = s+tap (s'+1)

    // XCD-aware mapping: XCD gets p in {2*xcd, 2*xcd+1} -> L2-resident weights
    const int i = blockIdx.x;
    const int xcd = i & 7;
    const int k = i >> 3;
    const int p = (xcd << 1) | (k & 1);
    const int b = k >> 1;
    const int lblk = b * PARTS_ + p;

    const int t = threadIdx.x;
    const int lane = t & 63;
    const int wid = __builtin_amdgcn_readfirstlane(t >> 6);
    const int nlane = lane & 15;
    const int klane = lane >> 4;

    // ---- zero pad rows ----
    for (int q = t; q < XSTRIDE; q += 256) {
        Xt[q] = 0;
        Xt[65 * XSTRIDE + q] = 0;
    }
    for (int q = t; q < HSTR; q += 256) {
        Ht2[q] = 0;
        Ht2[65 * HSTR + q] = 0;
    }

    // ---- stage x slice into Xt[s+1][c] ----
    if (xT) {
        const ushort* xb = xT + ((size_t)lblk * SEQ_) * CH_;
        const int half = lane >> 5;
        const int col8 = (lane & 31) * 8;
        #pragma unroll
        for (int kk = 0; kk < 8; ++kk) {
            const int row = kk * 8 + wid * 2 + half;   // s
            bf16x8 v = *reinterpret_cast<const bf16x8*>(xb + (size_t)row * CH_ + col8);
            *reinterpret_cast<bf16x8*>(&Xt[(row + 1) * XSTRIDE + col8]) = v;
        }
    } else {
        const float* xb = x + (size_t)b * (SEQ_ * CH_ * PARTS_) + p;
        for (int cc = wid; cc < CH_; cc += 4) {
            float v = xb[((size_t)lane * CH_ + cc) * PARTS_];
            Xt[(lane + 1) * XSTRIDE + cc] = f2bf(v);
        }
    }
    __syncthreads();

    // ---- stage 1: wave owns j-tile (j = wid*16 + nlane); computes all 64 s ----
    {
        const ushort* wa1 = ws + WA1_OFF + ((size_t)p * 96 * 64 * 8);
        const ushort* wa2 = ws + WA2_OFF + ((size_t)p * 96 * 64 * 8);
        const int j = (wid << 4) + nlane;
        // chunk kc = kk*4 + klane; addr = (kc*64 + j)*8
        #define WA_ADDR(base, kkv) ((base) + (((size_t)((kkv) * 4 + klane) * 64 + j) << 3))

        f32x4 acc1[4], acc2[4];
        #pragma unroll
        for (int st = 0; st < 4; ++st) { acc1[st] = {0.f,0.f,0.f,0.f}; acc2[st] = {0.f,0.f,0.f,0.f}; }

        bf16x8 pa1[2], pa2[2];
        pa1[0] = *reinterpret_cast<const bf16x8*>(WA_ADDR(wa1, 0));
        pa2[0] = *reinterpret_cast<const bf16x8*>(WA_ADDR(wa2, 0));
        pa1[1] = *reinterpret_cast<const bf16x8*>(WA_ADDR(wa1, 1));
        pa2[1] = *reinterpret_cast<const bf16x8*>(WA_ADDR(wa2, 1));

        const int coff = klane << 3;
        #pragma unroll 1
        for (int kk = 0; kk < 24; kk += 2) {
            {   // even sub-iter: uses pa[0], prefetch kk+2
                const int kn = (kk + 2 < 24) ? (kk + 2) : 22;
                bf16x8 n1 = *reinterpret_cast<const bf16x8*>(WA_ADDR(wa1, kn));
                bf16x8 n2 = *reinterpret_cast<const bf16x8*>(WA_ADDR(wa2, kn));
                const int tap = kk >> 3;
                const int c0 = ((kk & 7) << 5) + coff;
                const int rbase = nlane + tap;          // row = s + tap
                #pragma unroll
                for (int st = 0; st < 4; ++st) {
                    bf16x8 bf = *reinterpret_cast<const bf16x8*>(&Xt[((st << 4) + rbase) * XSTRIDE + c0]);
                    acc1[st] = __builtin_amdgcn_mfma_f32_16x16x32_bf16(pa1[0], bf, acc1[st], 0, 0, 0);
                    acc2[st] = __builtin_amdgcn_mfma_f32_16x16x32_bf16(pa2[0], bf, acc2[st], 0, 0, 0);
                }
                pa1[0] = n1; pa2[0] = n2;
            }
            {   // odd sub-iter: uses pa[1], prefetch kk+3
                const int k1 = kk + 1;
                const int kn = (k1 + 2 < 24) ? (k1 + 2) : 23;
                bf16x8 n1 = *reinterpret_cast<const bf16x8*>(WA_ADDR(wa1, kn));
                bf16x8 n2 = *reinterpret_cast<const bf16x8*>(WA_ADDR(wa2, kn));
                const int tap = k1 >> 3;
                const int c0 = ((k1 & 7) << 5) + coff;
                const int rbase = nlane + tap;
                #pragma unroll
                for (int st = 0; st < 4; ++st) {
                    bf16x8 bf = *reinterpret_cast<const bf16x8*>(&Xt[((st << 4) + rbase) * XSTRIDE + c0]);
                    acc1[st] = __builtin_amdgcn_mfma_f32_16x16x32_bf16(pa1[1], bf, acc1[st], 0, 0, 0);
                    acc2[st] = __builtin_amdgcn_mfma_f32_16x16x32_bf16(pa2[1], bf, acc2[st], 0, 0, 0);
                }
                pa1[1] = n1; pa2[1] = n2;
            }
        }
        #undef WA_ADDR

        // write Ht: D col = nlane -> s within tile; row = klane*4 + r -> j within tile
        #pragma unroll
        for (int st = 0; st < 4; ++st) {
            const int s = (st << 4) + nlane;
            const int jw = (wid << 4) + (klane << 2);
            #pragma unroll
            for (int r = 0; r < 4; ++r) {
                float v1 = acc1[st][r]; v1 = (v1 > 0.f) ? v1 : 0.01f * v1;
                Ht1[s * HSTR + jw + r] = f2bf(v1);
                float v2 = acc2[st][r]; v2 = (v2 > 0.f) ? v2 : 0.01f * v2;
                Ht2[(s + 1) * HSTR + jw + r] = f2bf(v2);
            }
        }
    }
    __syncthreads();

    // ---- stage 2 + epilogue: wave owns c-group (64 c), two st-pass halves ----
    const ushort* wb1 = ws + WB1_OFF + ((size_t)p * 8 * 256 * 8);
    const ushort* wb2 = ws + WB2_OFF + ((size_t)p * 24 * 256 * 8);

    float pmax[4][4];
    #pragma unroll
    for (int ctl = 0; ctl < 4; ++ctl)
        #pragma unroll
        for (int r = 0; r < 4; ++r) pmax[ctl][r] = -INFINITY;

    const int koff = klane << 3;

    #pragma unroll 1
    for (int half = 0; half < 2; ++half) {
        const int st0 = half << 1;
        f32x4 l1[4][2], l2[4][2];
        #pragma unroll
        for (int ctl = 0; ctl < 4; ++ctl) {
            l1[ctl][0] = {0.f,0.f,0.f,0.f}; l1[ctl][1] = {0.f,0.f,0.f,0.f};
            l2[ctl][0] = {0.f,0.f,0.f,0.f}; l2[ctl][1] = {0.f,0.f,0.f,0.f};
        }

        // branch 1: conv1x1, K = 64 (kc = kk*4 + klane)
        #pragma unroll
        for (int kk = 0; kk < 2; ++kk) {
            bf16x8 bfr0 = *reinterpret_cast<const bf16x8*>(
                &Ht1[(((st0 + 0) << 4) + nlane) * HSTR + (kk << 5) + koff]);
            bf16x8 bfr1 = *reinterpret_cast<const bf16x8*>(
                &Ht1[(((st0 + 1) << 4) + nlane) * HSTR + (kk << 5) + koff]);
            #pragma unroll
            for (int ctl = 0; ctl < 4; ++ctl) {
                const int c = (wid << 6) + (ctl << 4) + nlane;
                bf16x8 af = *reinterpret_cast<const bf16x8*>(
                    wb1 + ((((size_t)(kk * 4 + klane)) * 256 + c) << 3));
                l1[ctl][0] = __builtin_amdgcn_mfma_f32_16x16x32_bf16(af, bfr0, l1[ctl][0], 0, 0, 0);
                l1[ctl][1] = __builtin_amdgcn_mfma_f32_16x16x32_bf16(af, bfr1, l1[ctl][1], 0, 0, 0);
            }
        }
        // branch 2: conv3, K = 192 (k2 = tap*64 + h)
        #pragma unroll
        for (int kk = 0; kk < 6; ++kk) {
            const int tap = kk >> 1;
            const int h0 = ((kk & 1) << 5) + koff;
            bf16x8 bfr0 = *reinterpret_cast<const bf16x8*>(
                &Ht2[(((st0 + 0) << 4) + nlane + tap) * HSTR + h0]);
            bf16x8 bfr1 = *reinterpret_cast<const bf16x8*>(
                &Ht2[(((st0 + 1) << 4) + nlane + tap) * HSTR + h0]);
            #pragma unroll
            for (int ctl = 0; ctl < 4; ++ctl) {
                const int c = (wid << 6) + (ctl << 4) + nlane;
                bf16x8 af = *reinterpret_cast<const bf16x8*>(
                    wb2 + ((((size_t)(kk * 4 + klane)) * 256 + c) << 3));
                l2[ctl][0] = __builtin_amdgcn_mfma_f32_16x16x32_bf16(af, bfr0, l2[ctl][0], 0, 0, 0);
                l2[ctl][1] = __builtin_amdgcn_mfma_f32_16x16x32_bf16(af, bfr1, l2[ctl][1], 0, 0, 0);
            }
        }

        // partial epilogue for this half's two s-tiles
        #pragma unroll
        for (int ctl = 0; ctl < 4; ++ctl) {
            #pragma unroll
            for (int r = 0; r < 4; ++r) {
                const int c = (wid << 6) + (ctl << 4) + (klane << 2) + r;
                #pragma unroll
                for (int sh = 0; sh < 2; ++sh) {
                    const int s = ((st0 + sh) << 4) + nlane;
                    const int rm2 = (s >= 1) ? (s - 1) : 0;     // row for x[s-2]
                    const int rp2 = (s <= 62) ? (s + 3) : 65;   // row for x[s+2]
                    const float xm2 = bf2f(Xt[rm2 * XSTRIDE + c]);
                    const float xm1 = bf2f(Xt[(s)     * XSTRIDE + c]);
                    const float x0  = bf2f(Xt[(s + 1) * XSTRIDE + c]);
                    const float xp1 = bf2f(Xt[(s + 2) * XSTRIDE + c]);
                    const float xp2 = bf2f(Xt[rp2 * XSTRIDE + c]);
                    const float avg3 = (xm1 + x0 + xp1) * (1.f / 3.f);
                    const float avg5 = (xm2 + xm1 + x0 + xp1 + xp2) * 0.2f;
                    float mx3 = x0;
                    if (s > 0)  mx3 = fmaxf(mx3, xm1);
                    if (s < 63) mx3 = fmaxf(mx3, xp1);
                    float mx5 = mx3;
                    if (s > 1)  mx5 = fmaxf(mx5, xm2);
                    if (s < 62) mx5 = fmaxf(mx5, xp2);
                    const float g1 = 1.f / (1.f + __expf(-l1[ctl][sh][r]));
                    const float g2 = 1.f / (1.f + __expf(-l2[ctl][sh][r]));
                    const float m = (avg3 + mx3) * g1 + (avg5 + mx5) * g2;
                    pmax[ctl][r] = fmaxf(pmax[ctl][r], m);
                }
            }
        }
    }

    // ---- final reduce over nlane (s) and write ----
    #pragma unroll
    for (int ctl = 0; ctl < 4; ++ctl) {
        #pragma unroll
        for (int r = 0; r < 4; ++r) {
            float m = pmax[ctl][r];
            m = fmaxf(m, __shfl_xor(m, 1, 64));
            m = fmaxf(m, __shfl_xor(m, 2, 64));
            m = fmaxf(m, __shfl_xor(m, 4, 64));
            m = fmaxf(m, __shfl_xor(m, 8, 64));
            if (nlane == 0) {
                const int c = (wid << 6) + (ctl << 4) + (klane << 2) + r;
                out[(size_t)lblk * CH_ + c] = m;
            }
        }
    }
}

// ========== fallback (round-2 fp32 kernel) if ws too small ==========
#define HPAD 68
__global__ __launch_bounds__(256, 1) void tfa_fused_fp32(
    const float* __restrict__ x,
    const float* __restrict__ W1a,
    const float* __restrict__ W1b,
    const float* __restrict__ W2a,
    const float* __restrict__ W2b,
    float* __restrict__ out)
{
    __shared__ float xs[CH_ * SEQ_];
    __shared__ float h1s[HID_ * HPAD];
    __shared__ float h2s[HID_ * HPAD];

    const int blk = blockIdx.x;
    const int b = blk >> 4;
    const int p = blk & 15;
    const int t = threadIdx.x;
    const int lane = t & 63;
    const int wid = __builtin_amdgcn_readfirstlane(t >> 6);

    {
        const float* xb = x + (size_t)b * (SEQ_ * CH_ * PARTS_) + p;
        const int s = lane;
        for (int cc = wid; cc < CH_; cc += 4)
            xs[cc * SEQ_ + s] = xb[((size_t)s * CH_ + cc) * PARTS_];
    }
    __syncthreads();

    const int jj = lane & 15;
    const int sg = lane >> 4;
    const int sbase = sg << 4;
    const float fl = (sg > 0) ? 1.f : 0.f;
    const float fr = (sg < 3) ? 1.f : 0.f;
    const int il  = (sg > 0) ? -1 : 0;
    const int ir  = (sg < 3) ? 16 : 0;
    const int ir2 = (sg < 3) ? 17 : 0;
    const int il2 = (sg > 0) ? -2 : 0;

    {
        const int j0 = wid * 16 + jj;
        float a1[16], a2[16];
        #pragma unroll
        for (int q = 0; q < 16; ++q) { a1[q] = 0.f; a2[q] = 0.f; }
        const float* w1p = W1a + (size_t)(p * HID_ + j0) * (CH_ * 3);
        const float* w2p = W2a + (size_t)(p * HID_ + j0) * (CH_ * 3);
        #pragma unroll 4
        for (int c = 0; c < CH_; ++c) {
            const float* xrow = &xs[c * SEQ_ + sbase];
            float xv[18];
            {
                float4 q;
                q = *(const float4*)(xrow);      xv[1]=q.x; xv[2]=q.y; xv[3]=q.z; xv[4]=q.w;
                q = *(const float4*)(xrow + 4);  xv[5]=q.x; xv[6]=q.y; xv[7]=q.z; xv[8]=q.w;
                q = *(const float4*)(xrow + 8);  xv[9]=q.x; xv[10]=q.y; xv[11]=q.z; xv[12]=q.w;
                q = *(const float4*)(xrow + 12); xv[13]=q.x; xv[14]=q.y; xv[15]=q.z; xv[16]=q.w;
            }
            xv[0]  = xrow[il] * fl;
            xv[17] = xrow[ir] * fr;
            const float w10 = w1p[c*3+0], w11 = w1p[c*3+1], w12 = w1p[c*3+2];
            const float w20 = w2p[c*3+0], w21 = w2p[c*3+1], w22 = w2p[c*3+2];
            #pragma unroll
            for (int q = 0; q < 16; ++q) {
                a1[q] = fmaf(xv[q], w10, fmaf(xv[q+1], w11, fmaf(xv[q+2], w12, a1[q])));
                a2[q] = fmaf(xv[q], w20, fmaf(xv[q+1], w21, fmaf(xv[q+2], w22, a2[q])));
            }
        }
        float* h1w = &h1s[j0 * HPAD + sbase];
        float* h2w = &h2s[j0 * HPAD + sbase];
        #pragma unroll
        for (int q4 = 0; q4 < 4; ++q4) {
            float4 v1, v2; float u;
            u = a1[4*q4+0]; v1.x = (u>0.f)?u:0.01f*u;
            u = a1[4*q4+1]; v1.y = (u>0.f)?u:0.01f*u;
            u = a1[4*q4+2]; v1.z = (u>0.f)?u:0.01f*u;
            u = a1[4*q4+3]; v1.w = (u>0.f)?u:0.01f*u;
            u = a2[4*q4+0]; v2.x = (u>0.f)?u:0.01f*u;
            u = a2[4*q4+1]; v2.y = (u>0.f)?u:0.01f*u;
            u = a2[4*q4+2]; v2.z = (u>0.f)?u:0.01f*u;
            u = a2[4*q4+3]; v2.w = (u>0.f)?u:0.01f*u;
            *(float4*)(h1w + 4*q4) = v1;
            *(float4*)(h2w + 4*q4) = v2;
        }
    }
    __syncthreads();

    {
        const int cbase = wid * 64;
        float l1[4][16], l2[4][16];
        #pragma unroll
        for (int ch = 0; ch < 4; ++ch)
            #pragma unroll
            for (int q = 0; q < 16; ++q) { l1[ch][q] = 0.f; l2[ch][q] = 0.f; }
        #pragma unroll 2
        for (int h = 0; h < HID_; ++h) {
            const float* h1row = &h1s[h * HPAD + sbase];
            const float* h2row = &h2s[h * HPAD + sbase];
            float hv1[16], hv2[18];
            {
                float4 q;
                q = *(const float4*)(h1row);      hv1[0]=q.x; hv1[1]=q.y; hv1[2]=q.z; hv1[3]=q.w;
                q = *(const float4*)(h1row + 4);  hv1[4]=q.x; hv1[5]=q.y; hv1[6]=q.z; hv1[7]=q.w;
                q = *(const float4*)(h1row + 8);  hv1[8]=q.x; hv1[9]=q.y; hv1[10]=q.z; hv1[11]=q.w;
                q = *(const float4*)(h1row + 12); hv1[12]=q.x; hv1[13]=q.y; hv1[14]=q.z; hv1[15]=q.w;
                q = *(const float4*)(h2row);      hv2[1]=q.x; hv2[2]=q.y; hv2[3]=q.z; hv2[4]=q.w;
                q = *(const float4*)(h2row + 4);  hv2[5]=q.x; hv2[6]=q.y; hv2[7]=q.z; hv2[8]=q.w;
                q = *(const float4*)(h2row + 8);  hv2[9]=q.x; hv2[10]=q.y; hv2[11]=q.z; hv2[12]=q.w;
                q = *(const float4*)(h2row + 12); hv2[13]=q.x; hv2[14]=q.y; hv2[15]=q.z; hv2[16]=q.w;
            }
            hv2[0]  = h2row[il] * fl;
            hv2[17] = h2row[ir] * fr;
            #pragma unroll
            for (int ch = 0; ch < 4; ++ch) {
                const int c = cbase + ch * 16 + jj;
                const float wb1 = W1b[((size_t)p * CH_ + c) * HID_ + h];
                const float* w2q = W2b + ((size_t)(p * CH_ + c) * HID_ + h) * 3;
                const float wa = w2q[0], wb = w2q[1], wc = w2q[2];
                #pragma unroll
                for (int q = 0; q < 16; ++q) {
                    l1[ch][q] = fmaf(hv1[q], wb1, l1[ch][q]);
                    l2[ch][q] = fmaf(hv2[q], wa, fmaf(hv2[q+1], wb, fmaf(hv2[q+2], wc, l2[ch][q])));
                }
            }
        }
        #pragma unroll
        for (int ch = 0; ch < 4; ++ch) {
            const int c = cbase + ch * 16 + jj;
            const float* xrow = &xs[c * SEQ_ + sbase];
            float xp[20];
            {
                float4 q;
                q = *(const float4*)(xrow);      xp[2]=q.x; xp[3]=q.y; xp[4]=q.z; xp[5]=q.w;
                q = *(const float4*)(xrow + 4);  xp[6]=q.x; xp[7]=q.y; xp[8]=q.z; xp[9]=q.w;
                q = *(const float4*)(xrow + 8);  xp[10]=q.x; xp[11]=q.y; xp[12]=q.z; xp[13]=q.w;
                q = *(const float4*)(xrow + 12); xp[14]=q.x; xp[15]=q.y; xp[16]=q.z; xp[17]=q.w;
            }
            xp[0]  = xrow[il2] * fl;
            xp[1]  = xrow[il]  * fl;
            xp[18] = xrow[ir]  * fr;
            xp[19] = xrow[ir2] * fr;
            float mloc = -INFINITY;
            #pragma unroll
            for (int q = 0; q < 16; ++q) {
                const int s = sbase + q;
                const float x0  = xp[q+2];
                const float am1 = xp[q+1], ap1 = xp[q+3];
                const float am2 = xp[q],   ap2 = xp[q+4];
                const float avg3 = (am1 + x0 + ap1) * (1.f / 3.f);
                const float avg5 = (am2 + am1 + x0 + ap1 + ap2) * 0.2f;
                float mx3 = x0;
                if (s > 0)  mx3 = fmaxf(mx3, am1);
                if (s < 63) mx3 = fmaxf(mx3, ap1);
                float mx5 = mx3;
                if (s > 1)  mx5 = fmaxf(mx5, am2);
                if (s < 62) mx5 = fmaxf(mx5, ap2);
                const float g1 = 1.f / (1.f + __expf(-l1[ch][q]));
                const float g2 = 1.f / (1.f + __expf(-l2[ch][q]));
                const float m = (avg3 + mx3) * g1 + (avg5 + mx5) * g2;
                mloc = fmaxf(mloc, m);
            }
            mloc = fmaxf(mloc, __shfl_xor(mloc, 16, 64));
            mloc = fmaxf(mloc, __shfl_xor(mloc, 32, 64));
            if (sg == 0)
                out[(size_t)blk * CH_ + c] = mloc;
        }
    }
}

extern "C" void kernel_launch(void* const* d_in, const int* in_sizes, int n_in,
                              void* d_out, int out_size, void* d_ws, size_t ws_size,
                              hipStream_t stream) {
    const float* x   = (const float*)d_in[0];
    const float* W1a = (const float*)d_in[1];
    const float* W1b = (const float*)d_in[2];
    const float* W2a = (const float*)d_in[3];
    const float* W2b = (const float*)d_in[4];
    float* out = (float*)d_out;

    if (ws_size >= WS_BYTES) {
        ushort* ws = (ushort*)d_ws;
        const int nthreads = 16 * 96 * 64 * 8 + 16 * 8 * 256 * 8 + 16 * 24 * 256 * 8;
        prep_weights<<<dim3((nthreads + 255) / 256), dim3(256), 0, stream>>>(W1a, W1b, W2a, W2b, ws);
        ushort* xT = nullptr;
        if (ws_size >= WS_FULL_BYTES) {
            xT = ws + WS_ELEMS;
            prep_x<<<dim3(B_ * SEQ_), dim3(256), 0, stream>>>(x, xT);
        }
        tfa_mfma<<<dim3(B_ * PARTS_), dim3(256), 0, stream>>>(x, ws, xT, out);
    } else {
        tfa_fused_fp32<<<dim3(B_ * PARTS_), dim3(256), 0, stream>>>(x, W1a, W1b, W2a, W2b, out);
    }
}